// Round 1
// baseline (400.057 us; speedup 1.0000x reference)
//
#include <hip/hip_runtime.h>
#include <stdint.h>

// Problem constants (from reference): GRID=4096, windows (128,256,512) centered
// at (2048,2048). Output = [3,4096,4096] float masks flat, then 3 counts.
#define GRID_N 4096
#define MERGE_BLOCKS 1344   // 64 (128^2) + 256 (256^2) + 1024 (512^2) blocks of 256
#define ZERO_BLOCKS 8192

// Decode block id -> window params. Windows: w=0:S=128 off=1984, w=1:S=256 off=1920,
// w=2:S=512 off=1792. Label-array offsets: 0, 16384, 81920 (total 344064 ints in ws).
__device__ inline void decode_block(int b, int& w, int& S, int& lg, int& off,
                                    int& woff, int& baseblk) {
    if (b < 64)       { w = 0; S = 128; lg = 7; off = 1984; woff = 0;     baseblk = 0;   }
    else if (b < 320) { w = 1; S = 256; lg = 8; off = 1920; woff = 16384; baseblk = 64;  }
    else              { w = 2; S = 512; lg = 9; off = 1792; woff = 81920; baseblk = 320; }
}

// Union-find with device-scope atomic loads (per-XCD L2s are not coherent for
// plain loads under concurrent writes; relaxed agent-scope loads are).
__device__ inline int uf_find(int* L, int a) {
    int p = __hip_atomic_load(&L[a], __ATOMIC_RELAXED, __HIP_MEMORY_SCOPE_AGENT);
    while (p != a) {
        a = p;
        p = __hip_atomic_load(&L[a], __ATOMIC_RELAXED, __HIP_MEMORY_SCOPE_AGENT);
    }
    return a;
}

// Lock-free union: atomicMin on the larger root; on failure the old value is
// carried forward and re-merged, so overwritten links are always repaired.
__device__ inline void uf_union(int* L, int a, int b) {
    while (true) {
        a = uf_find(L, a);
        b = uf_find(L, b);
        if (a == b) return;
        if (a < b) { int t = a; a = b; b = t; }   // a > b: attach a under b
        int old = atomicMin(&L[a], b);
        if (old == a) return;                      // was a root, attached
        a = old;                                   // lost race: merge old link too
    }
}

// K1: init labels for all three windows: free cell -> own index, blocked -> -1.
__global__ void k_init(const float* __restrict__ mask, int* __restrict__ L) {
    int w, S, lg, off, woff, baseblk;
    decode_block(blockIdx.x, w, S, lg, off, woff, baseblk);
    int idx = (blockIdx.x - baseblk) * 256 + threadIdx.x;
    int r = idx >> lg;
    int c = idx & (S - 1);
    size_t g = (size_t)(off + r) * GRID_N + (size_t)(off + c);
    bool fr = (mask[g] == 0.0f);
    L[woff + idx] = fr ? idx : -1;
}

// K2: first MERGE_BLOCKS blocks do union-find merging (right+down edges);
// remaining blocks zero-fill the entire output buffer (201 MB) concurrently.
__global__ void k_merge_zero(int* __restrict__ L, float* __restrict__ out,
                             int out_size) {
    int b = blockIdx.x;
    if (b < MERGE_BLOCKS) {
        int w, S, lg, off, woff, baseblk;
        decode_block(b, w, S, lg, off, woff, baseblk);
        int idx = (b - baseblk) * 256 + threadIdx.x;
        int* Lw = L + woff;
        if (Lw[idx] == -1) return;                 // blocked: -1 is stable post-K1
        int r = idx >> lg;
        int c = idx & (S - 1);
        if (c + 1 < S && Lw[idx + 1] != -1) uf_union(Lw, idx, idx + 1);
        if (r + 1 < S && Lw[idx + S] != -1) uf_union(Lw, idx, idx + S);
    } else {
        long long n4 = (long long)(out_size >> 2);
        long long i = (long long)(b - MERGE_BLOCKS) * 256 + threadIdx.x;
        long long stride = (long long)(gridDim.x - MERGE_BLOCKS) * 256;
        float4* o4 = (float4*)out;
        float4 z = make_float4(0.f, 0.f, 0.f, 0.f);
        for (; i < n4; i += stride) o4[i] = z;
        // tail (the 3 count slots): zeroed so K3's atomicAdd accumulates from 0
        long long t = (long long)(b - MERGE_BLOCKS) * 256 + threadIdx.x;
        long long tail = (long long)out_size - n4 * 4;
        if (t < tail) out[n4 * 4 + t] = 0.0f;
    }
}

// K3: per cell, reach = free && find(cell)==find(center); scatter into the full
// grid window region; ballot-popcount reduction -> one float atomicAdd per block
// into the count slots (counts < 2^24, exact in fp32).
__global__ void k_write(int* __restrict__ L, float* __restrict__ out) {
    int b = blockIdx.x;
    int w, S, lg, off, woff, baseblk;
    decode_block(b, w, S, lg, off, woff, baseblk);
    int idx = (b - baseblk) * 256 + threadIdx.x;
    int* Lw = L + woff;

    __shared__ int rootC;
    __shared__ float wsum[4];
    if (threadIdx.x == 0) {
        int centerIdx = (S >> 1) * S + (S >> 1);   // center is always free (setup)
        rootC = uf_find(Lw, centerIdx);
    }
    __syncthreads();

    int lab = Lw[idx];
    bool reach = false;
    if (lab != -1) {
        int root = uf_find(Lw, idx);
        Lw[idx] = root;                            // path compression (benign race)
        reach = (root == rootC);
    }
    int r = idx >> lg;
    int c = idx & (S - 1);
    size_t go = (size_t)w * GRID_N * GRID_N + (size_t)(off + r) * GRID_N + (size_t)(off + c);
    out[go] = reach ? 1.0f : 0.0f;

    unsigned long long m = __ballot(reach);
    int lane = threadIdx.x & 63;
    int wv = threadIdx.x >> 6;
    if (lane == 0) wsum[wv] = (float)__popcll(m);
    __syncthreads();
    if (threadIdx.x == 0) {
        float s = wsum[0] + wsum[1] + wsum[2] + wsum[3];
        atomicAdd(&out[(size_t)3 * GRID_N * GRID_N + w], s);
    }
}

extern "C" void kernel_launch(void* const* d_in, const int* in_sizes, int n_in,
                              void* d_out, int out_size, void* d_ws, size_t ws_size,
                              hipStream_t stream) {
    const float* mask = (const float*)d_in[0];
    float* out = (float*)d_out;
    int* L = (int*)d_ws;   // needs 344064 * 4 B = 1.35 MB of workspace

    k_init<<<MERGE_BLOCKS, 256, 0, stream>>>(mask, L);
    k_merge_zero<<<MERGE_BLOCKS + ZERO_BLOCKS, 256, 0, stream>>>(L, out, out_size);
    k_write<<<MERGE_BLOCKS, 256, 0, stream>>>(L, out);
}

// Round 3
// 273.978 us; speedup vs baseline: 1.4602x; 1.4602x over previous
//
#include <hip/hip_runtime.h>
#include <stdint.h>

// GRID=4096, windows (128,256,512) centered at (2048,2048).
// Output = [3,4096,4096] float masks flat, then 3 counts.
#define GRID_N 4096
#define CELL_BLOCKS 1344    // 64 + 256 + 1024 blocks of 256 (one thread per cell)
#define TILE_BLOCKS 336     // 16 + 64 + 256 tiles of 32x32
#define EDGE_BLOCKS 77      // 19712 boundary edges / 256
#define ZERO_BLOCKS 8192

typedef float vfloat4 __attribute__((ext_vector_type(4)));

// ---- window decode for cell-per-thread kernels (256 threads/block) ----
__device__ inline void decode_block(int b, int& w, int& S, int& lg, int& off,
                                    int& woff, int& baseblk) {
    if (b < 64)       { w = 0; S = 128; lg = 7; off = 1984; woff = 0;     baseblk = 0;   }
    else if (b < 320) { w = 1; S = 256; lg = 8; off = 1920; woff = 16384; baseblk = 64;  }
    else              { w = 2; S = 512; lg = 9; off = 1792; woff = 81920; baseblk = 320; }
}

// ---- tile decode for k_local (32x32 tile per block) ----
__device__ inline void decode_tile(int b, int& S, int& lg, int& off, int& woff,
                                   int& tileR, int& tileC) {
    int t, tsh;
    if (b < 16)      { S = 128; lg = 7; off = 1984; woff = 0;     t = b;      tsh = 2; }
    else if (b < 80) { S = 256; lg = 8; off = 1920; woff = 16384; t = b - 16; tsh = 3; }
    else             { S = 512; lg = 9; off = 1792; woff = 81920; t = b - 80; tsh = 4; }
    tileR = t >> tsh;
    tileC = t & ((1 << tsh) - 1);
}

// ---- global union-find (device-scope; carry-forward atomicMin union) ----
__device__ inline int uf_find(int* L, int a) {
    int p = __hip_atomic_load(&L[a], __ATOMIC_RELAXED, __HIP_MEMORY_SCOPE_AGENT);
    while (p != a) {
        a = p;
        p = __hip_atomic_load(&L[a], __ATOMIC_RELAXED, __HIP_MEMORY_SCOPE_AGENT);
    }
    return a;
}
__device__ inline void uf_union(int* L, int a, int b) {
    while (true) {
        a = uf_find(L, a);
        b = uf_find(L, b);
        if (a == b) return;
        if (a < b) { int t = a; a = b; b = t; }
        int old = atomicMin(&L[a], b);
        if (old == a) return;
        a = old;
    }
}

// ---- LDS union-find (workgroup scope) ----
__device__ inline int lfind(int* lab, int a) {
    int p = __hip_atomic_load(&lab[a], __ATOMIC_RELAXED, __HIP_MEMORY_SCOPE_WORKGROUP);
    while (p != a) {
        a = p;
        p = __hip_atomic_load(&lab[a], __ATOMIC_RELAXED, __HIP_MEMORY_SCOPE_WORKGROUP);
    }
    return a;
}
__device__ inline void lunion(int* lab, int a, int b) {
    while (true) {
        a = lfind(lab, a);
        b = lfind(lab, b);
        if (a == b) return;
        if (a < b) { int t = a; a = b; b = t; }
        int old = atomicMin(&lab[a], b);
        if (old == a) return;
        a = old;
    }
}

// K1: per-tile CCL in LDS; emit global labels pointing at tile-local roots
// (depth-1 forest in window-linear index space), blocked = -1.
__global__ void k_local(const float* __restrict__ mask, int* __restrict__ L) {
    int S, lg, off, woff, tileR, tileC;
    decode_tile(blockIdx.x, S, lg, off, woff, tileR, tileC);
    __shared__ int lab[1024];

    #pragma unroll
    for (int k = 0; k < 4; k++) {
        int l = threadIdx.x + k * 256;
        int lr = l >> 5, lc = l & 31;
        int gr = tileR * 32 + lr, gc = tileC * 32 + lc;
        size_t g = (size_t)(off + gr) * GRID_N + (size_t)(off + gc);
        lab[l] = (mask[g] == 0.0f) ? l : -1;
    }
    __syncthreads();

    #pragma unroll
    for (int k = 0; k < 4; k++) {
        int l = threadIdx.x + k * 256;
        if (lab[l] == -1) continue;
        int lr = l >> 5, lc = l & 31;
        if (lc + 1 < 32 && lab[l + 1] != -1)  lunion(lab, l, l + 1);
        if (lr + 1 < 32 && lab[l + 32] != -1) lunion(lab, l, l + 32);
    }
    __syncthreads();

    #pragma unroll
    for (int k = 0; k < 4; k++) {
        int l = threadIdx.x + k * 256;
        int lr = l >> 5, lc = l & 31;
        int gidx = (tileR * 32 + lr) * S + tileC * 32 + lc;
        if (lab[l] == -1) {
            L[woff + gidx] = -1;
        } else {
            int r = lfind(lab, l);
            int rr = r >> 5, rc = r & 31;
            L[woff + gidx] = (tileR * 32 + rr) * S + tileC * 32 + rc;
        }
    }
}

// K2: first EDGE_BLOCKS blocks union tile-boundary edges; remaining blocks
// zero-fill the whole 201 MB output (nontemporal float4 stores).
__global__ void k_zero_merge(int* __restrict__ L, float* __restrict__ out,
                             int out_size) {
    int b = blockIdx.x;
    if (b < EDGE_BLOCKS) {
        int e = b * 256 + threadIdx.x;
        // ranges: [0,384) w0-h, [384,768) w0-v, [768,2560) w1-h,
        //         [2560,4352) w1-v, [4352,12032) w2-h, [12032,19712) w2-v
        int S, lg, woff, i; bool horiz;
        if (e < 768)        { S = 128; lg = 7; woff = 0;     horiz = e < 384;   i = horiz ? e : e - 384; }
        else if (e < 4352)  { S = 256; lg = 8; woff = 16384; horiz = e < 2560;  i = horiz ? e - 768 : e - 2560; }
        else                { S = 512; lg = 9; woff = 81920; horiz = e < 12032; i = horiz ? e - 4352 : e - 12032; }
        int bi = i >> lg;
        int* Lw = L + woff;
        int a, n;
        if (horiz) { int r = i & (S - 1); int c = bi * 32 + 31; a = r * S + c; n = a + 1; }
        else       { int c = i & (S - 1); int r = bi * 32 + 31; a = r * S + c; n = a + S; }
        if (Lw[a] != -1 && Lw[n] != -1) uf_union(Lw, a, n);
    } else {
        long long n4 = (long long)(out_size >> 2);
        long long i = (long long)(b - EDGE_BLOCKS) * 256 + threadIdx.x;
        long long stride = (long long)(gridDim.x - EDGE_BLOCKS) * 256;
        vfloat4* o4 = (vfloat4*)out;
        vfloat4 z = (vfloat4)(0.0f);
        for (; i < n4; i += stride) __builtin_nontemporal_store(z, &o4[i]);
        long long t = (long long)(b - EDGE_BLOCKS) * 256 + threadIdx.x;
        long long tail = (long long)out_size - n4 * 4;
        if (t < tail) out[n4 * 4 + t] = 0.0f;
    }
}

// K3: reach = free && find(cell)==find(center); scatter window masks; counts
// via ballot-popcount -> one float atomicAdd per block.
__global__ void k_write(int* __restrict__ L, float* __restrict__ out) {
    int b = blockIdx.x;
    int w, S, lg, off, woff, baseblk;
    decode_block(b, w, S, lg, off, woff, baseblk);
    int idx = (b - baseblk) * 256 + threadIdx.x;
    int* Lw = L + woff;

    __shared__ int rootC;
    __shared__ float wsum[4];
    if (threadIdx.x == 0) {
        int centerIdx = (S >> 1) * S + (S >> 1);   // center is always free (setup)
        rootC = uf_find(Lw, centerIdx);
    }
    __syncthreads();

    int lab = Lw[idx];
    bool reach = false;
    if (lab != -1) {
        int root = uf_find(Lw, idx);
        Lw[idx] = root;                            // path compression (benign race)
        reach = (root == rootC);
    }
    int r = idx >> lg;
    int c = idx & (S - 1);
    size_t go = (size_t)w * GRID_N * GRID_N + (size_t)(off + r) * GRID_N + (size_t)(off + c);
    out[go] = reach ? 1.0f : 0.0f;

    unsigned long long m = __ballot(reach);
    int lane = threadIdx.x & 63;
    int wv = threadIdx.x >> 6;
    if (lane == 0) wsum[wv] = (float)__popcll(m);
    __syncthreads();
    if (threadIdx.x == 0) {
        float s = wsum[0] + wsum[1] + wsum[2] + wsum[3];
        atomicAdd(&out[(size_t)3 * GRID_N * GRID_N + w], s);
    }
}

extern "C" void kernel_launch(void* const* d_in, const int* in_sizes, int n_in,
                              void* d_out, int out_size, void* d_ws, size_t ws_size,
                              hipStream_t stream) {
    const float* mask = (const float*)d_in[0];
    float* out = (float*)d_out;
    int* L = (int*)d_ws;   // 344064 * 4 B = 1.35 MB of workspace

    k_local<<<TILE_BLOCKS, 256, 0, stream>>>(mask, L);
    k_zero_merge<<<EDGE_BLOCKS + ZERO_BLOCKS, 256, 0, stream>>>(L, out, out_size);
    k_write<<<CELL_BLOCKS, 256, 0, stream>>>(L, out);
}